// Round 3
// baseline (9538.281 us; speedup 1.0000x reference)
//
#include <hip/hip_runtime.h>
#include <math.h>

// Problem constants
#define B_   4096
#define D_   256
#define H_   266
#define T_   51
#define S_   50
#define HP   272        // padded fp32 activation row stride
#define EPSF 1e-5f
#define NB   192        // persistent grid (< 256 CUs -> all co-resident)

typedef __bf16 bf16_t;
typedef __bf16 bf16x8 __attribute__((ext_vector_type(8)));
typedef float  f32x4  __attribute__((ext_vector_type(4)));

#define BM 128
#define BN 128
#define LDST 40   // LDS row stride (bf16)

// ---------------- grid barrier (agent scope, sense via generation) ----------
__device__ __forceinline__ void gsync(unsigned* cnt, unsigned* gen, unsigned nb) {
  __syncthreads();
  if (threadIdx.x == 0) {
    __threadfence();  // release: make my global writes device-visible
    unsigned g = __hip_atomic_load(gen, __ATOMIC_RELAXED, __HIP_MEMORY_SCOPE_AGENT);
    unsigned arrived = __hip_atomic_fetch_add(cnt, 1u, __ATOMIC_ACQ_REL, __HIP_MEMORY_SCOPE_AGENT);
    if (arrived == nb - 1u) {
      __hip_atomic_store(cnt, 0u, __ATOMIC_RELAXED, __HIP_MEMORY_SCOPE_AGENT);
      __hip_atomic_fetch_add(gen, 1u, __ATOMIC_RELEASE, __HIP_MEMORY_SCOPE_AGENT);
    } else {
      while (__hip_atomic_load(gen, __ATOMIC_ACQUIRE, __HIP_MEMORY_SCOPE_AGENT) == g)
        __builtin_amdgcn_s_sleep(1);
    }
    __threadfence();  // acquire: invalidate stale cached lines
  }
  __syncthreads();
}

// ---------------- 128x128 bf16 MFMA tile: acc = A(fp32,opt BN+relu) @ Wt^T ---
__device__ __forceinline__ void gemm_tile(
    const float* __restrict__ A, int lda, int Ka,
    int bnA, const float* __restrict__ g, const float* __restrict__ be,
    const float* __restrict__ asum, const float* __restrict__ asq, float invB,
    const bf16_t* __restrict__ Wt, int ldw, int N, int r0, int c0,
    bf16_t (*As)[LDST], bf16_t (*Ws)[LDST], float* sc, float* sh,
    f32x4 acc[4][4])
{
  const int tid = threadIdx.x;
  if (bnA) {
    for (int k = tid; k < 288; k += 256) {
      if (k < Ka) {
        float mu  = asum[k] * invB;
        float var = asq[k] * invB - mu * mu;
        float s   = g[k] * rsqrtf(var + EPSF);
        sc[k] = s; sh[k] = be[k] - mu * s;
      } else { sc[k] = 0.f; sh[k] = 0.f; }
    }
  }
  #pragma unroll
  for (int mi = 0; mi < 4; ++mi)
    #pragma unroll
    for (int ni = 0; ni < 4; ++ni)
      acc[mi][ni] = (f32x4){0.f, 0.f, 0.f, 0.f};

  const int lane = tid & 63;
  const int wave = tid >> 6;
  const int wr = (wave >> 1) * 64;
  const int wc = (wave & 1) * 64;
  const int l16 = lane & 15;
  const int lk8 = (lane >> 4) * 8;
  const int arow  = tid >> 1;
  const int akseg = (tid & 1) * 16;

  const int niter = (Ka + 31) / 32;
  for (int it = 0; it < niter; ++it) {
    const int k0 = it * 32;
    float a16[16];
    const float* Ap = A + (size_t)(r0 + arow) * lda + k0 + akseg;
    if (k0 + 32 <= Ka) {
      const float4* p = (const float4*)Ap;
      float4 v0 = p[0], v1 = p[1], v2 = p[2], v3 = p[3];
      a16[0]=v0.x; a16[1]=v0.y; a16[2]=v0.z; a16[3]=v0.w;
      a16[4]=v1.x; a16[5]=v1.y; a16[6]=v1.z; a16[7]=v1.w;
      a16[8]=v2.x; a16[9]=v2.y; a16[10]=v2.z; a16[11]=v2.w;
      a16[12]=v3.x; a16[13]=v3.y; a16[14]=v3.z; a16[15]=v3.w;
    } else {
      #pragma unroll
      for (int i = 0; i < 16; ++i) {
        int k = k0 + akseg + i;
        a16[i] = (k < Ka) ? Ap[i] : 0.f;
      }
    }
    uint4 wv0 = make_uint4(0,0,0,0), wv1 = make_uint4(0,0,0,0);
    {
      int cr = c0 + arow;
      if (cr < N) {
        const uint4* p = (const uint4*)(Wt + (size_t)cr * ldw + k0 + akseg);
        wv0 = p[0]; wv1 = p[1];
      }
    }
    __syncthreads();   // prior LDS uses done
    bf16x8 p0, p1;
    if (bnA) {
      #pragma unroll
      for (int i = 0; i < 8; ++i) {
        int k = k0 + akseg + i;
        p0[i] = (bf16_t)fmaxf(fmaf(a16[i], sc[k], sh[k]), 0.f);
      }
      #pragma unroll
      for (int i = 0; i < 8; ++i) {
        int k = k0 + akseg + 8 + i;
        p1[i] = (bf16_t)fmaxf(fmaf(a16[8+i], sc[k], sh[k]), 0.f);
      }
    } else {
      #pragma unroll
      for (int i = 0; i < 8; ++i) p0[i] = (bf16_t)a16[i];
      #pragma unroll
      for (int i = 0; i < 8; ++i) p1[i] = (bf16_t)a16[8+i];
    }
    *(bf16x8*)&As[arow][akseg]     = p0;
    *(bf16x8*)&As[arow][akseg + 8] = p1;
    *(uint4*)&Ws[arow][akseg]      = wv0;
    *(uint4*)&Ws[arow][akseg + 8]  = wv1;
    __syncthreads();

    bf16x8 af[4], bfr[4];
    #pragma unroll
    for (int mi = 0; mi < 4; ++mi)
      af[mi] = *(const bf16x8*)&As[wr + mi*16 + l16][lk8];
    #pragma unroll
    for (int ni = 0; ni < 4; ++ni)
      bfr[ni] = *(const bf16x8*)&Ws[wc + ni*16 + l16][lk8];
    #pragma unroll
    for (int mi = 0; mi < 4; ++mi)
      #pragma unroll
      for (int ni = 0; ni < 4; ++ni)
        acc[mi][ni] = __builtin_amdgcn_mfma_f32_16x16x32_bf16(af[mi], bfr[ni], acc[mi][ni], 0, 0, 0);
  }
}

// ---------------- epilogues --------------------------------------------------
__device__ __forceinline__ void epi_store(
    float* __restrict__ C, int ldc, int N, int r0, int c0,
    const float* __restrict__ bias, const float* __restrict__ trow, float tcoef,
    int relu, float* ssum, float* ssq, f32x4 acc[4][4])
{
  const int tid = threadIdx.x, lane = tid & 63, wave = tid >> 6;
  const int wr = (wave >> 1) * 64, wc = (wave & 1) * 64;
  const int l16 = lane & 15, quad = lane >> 4;
  #pragma unroll
  for (int ni = 0; ni < 4; ++ni) {
    int col = c0 + wc + ni*16 + l16;
    bool cok = col < N;
    float b = cok ? bias[col] : 0.f;
    if (trow && cok) b = fmaf(tcoef, trow[col], b);
    float s = 0.f, q = 0.f;
    #pragma unroll
    for (int mi = 0; mi < 4; ++mi)
      #pragma unroll
      for (int r = 0; r < 4; ++r) {
        float v = acc[mi][ni][r] + b;
        if (relu) v = fmaxf(v, 0.f);
        int row = r0 + wr + mi*16 + quad*4 + r;
        if (cok) C[(size_t)row * ldc + col] = v;
        s += v; q += v * v;
      }
    if (ssum) {
      s += __shfl_xor(s, 16); q += __shfl_xor(q, 16);
      s += __shfl_xor(s, 32); q += __shfl_xor(q, 32);
      if (lane < 16) {
        int c2 = c0 + wc + ni*16 + lane;
        if (c2 < N) { atomicAdd(&ssum[c2], s); atomicAdd(&ssq[c2], q); }
      }
    }
  }
}

__device__ __forceinline__ void epi_grad(
    const float* __restrict__ bias, const float* __restrict__ xi_i,
    float* __restrict__ v, float sq, int r0, int c0, f32x4 acc[4][4])
{
  const int tid = threadIdx.x, lane = tid & 63, wave = tid >> 6;
  const int wr = (wave >> 1) * 64, wc = (wave & 1) * 64;
  const int l16 = lane & 15, quad = lane >> 4;
  #pragma unroll
  for (int mi = 0; mi < 4; ++mi)
    #pragma unroll
    for (int r = 0; r < 4; ++r) {
      int row = r0 + wr + mi*16 + quad*4 + r;
      float part = 0.f;
      #pragma unroll
      for (int ni = 0; ni < 4; ++ni) {
        int col = c0 + wc + ni*16 + l16;
        float gr = acc[mi][ni][r] + bias[col];
        part = fmaf(gr, xi_i[(size_t)row * D_ + col], part);
      }
      part += __shfl_xor(part, 1); part += __shfl_xor(part, 2);
      part += __shfl_xor(part, 4); part += __shfl_xor(part, 8);
      if (l16 == 0) atomicAdd(&v[row], sq * part);
    }
}

__device__ __forceinline__ void epi_alpha(
    const float* __restrict__ bias, const float* __restrict__ xc,
    const float* __restrict__ xi_i, const float* __restrict__ law_i,
    float* __restrict__ xn, float* __restrict__ v,
    float hi, float sq, int r0, int c0, f32x4 acc[4][4])
{
  const int tid = threadIdx.x, lane = tid & 63, wave = tid >> 6;
  const int wr = (wave >> 1) * 64, wc = (wave & 1) * 64;
  const int l16 = lane & 15, quad = lane >> 4;
  #pragma unroll
  for (int mi = 0; mi < 4; ++mi)
    #pragma unroll
    for (int r = 0; r < 4; ++r) {
      int row = r0 + wr + mi*16 + quad*4 + r;
      float part = 0.f;
      #pragma unroll
      for (int ni = 0; ni < 4; ++ni) {
        int col = c0 + wc + ni*16 + l16;
        size_t off = (size_t)row * D_ + col;
        float al  = acc[mi][ni][r] + bias[col];
        float xcv = xc[off], xiv = xi_i[off], lw = law_i[col];
        xn[off] = fmaf(al, hi, xcv) + sq * xiv;
        float d = xcv - lw;
        part = fmaf(al, al, part);
        part = fmaf(d, d, part);
      }
      part += __shfl_xor(part, 1); part += __shfl_xor(part, 2);
      part += __shfl_xor(part, 4); part += __shfl_xor(part, 8);
      if (l16 == 0) atomicAdd(&v[row], -0.5f * hi * part);
    }
}

// ---------------- persistent scan kernel ------------------------------------
struct ScanArgs {
  float* path; float* v;
  float* h1; float* h2; float* ah; float* yraw;
  float* stats;
  const bf16_t *W1t, *W2t, *W3t, *aW1t, *aW2t, *vW1t, *vW2t;
  const float *b1, *g1, *be1, *b2, *g2, *be2, *b3;
  const float *vb1, *vg1, *vbe1, *vb2, *vg2, *vbe2, *vW3, *vb3, *vg3, *vbe3;
  const float *ab1, *ab2, *aW1, *law, *tg, *xi;
  unsigned* bar;
};

__global__ __launch_bounds__(256) void scan_kernel(ScanArgs a) {
  __shared__ bf16_t As[BM][LDST];
  __shared__ bf16_t Ws[BN][LDST];
  __shared__ float sc[288], sh[288];
  __shared__ float sred[256];

  const int bid = blockIdx.x, tid = threadIdx.x;
  const unsigned nb = gridDim.x;
  const float invB = 1.0f / (float)B_;
  unsigned* cnt = a.bar; unsigned* gen = a.bar + 1;
  float* stats = a.stats;

  // ---- v0 stage 1 ----
  for (int t = bid; t < 96; t += nb) {
    int c0 = (t % 3) * 128, r0 = (t / 3) * 128;
    f32x4 acc[4][4];
    gemm_tile(a.path, D_, D_, 0, nullptr, nullptr, nullptr, nullptr, invB,
              a.vW1t, 256, H_, r0, c0, As, Ws, sc, sh, acc);
    epi_store(a.h1, HP, H_, r0, c0, a.vb1, nullptr, 0.f, 0,
              stats + 100*2*HP, stats + 100*2*HP + HP, acc);
  }
  gsync(cnt, gen, nb);
  // ---- v0 stage 2 ----
  for (int t = bid; t < 96; t += nb) {
    int c0 = (t % 3) * 128, r0 = (t / 3) * 128;
    f32x4 acc[4][4];
    gemm_tile(a.h1, HP, H_, 1, a.vg1, a.vbe1, stats + 100*2*HP, stats + 100*2*HP + HP, invB,
              a.vW2t, 288, H_, r0, c0, As, Ws, sc, sh, acc);
    epi_store(a.h2, HP, H_, r0, c0, a.vb2, nullptr, 0.f, 0,
              stats + 101*2*HP, stats + 101*2*HP + HP, acc);
  }
  gsync(cnt, gen, nb);
  // ---- v0 stage 3: matvec with BN on h2 ----
  {
    const float* s1 = stats + 101*2*HP; const float* q1 = s1 + HP;
    float* s2 = stats + 102*2*HP; float* q2 = s2 + HP;
    for (int r = bid; r < B_; r += nb) {
      float p = 0.f;
      for (int k = tid; k < H_; k += 256) {
        float mu = s1[k] * invB, var = q1[k] * invB - mu * mu;
        float s = a.vg2[k] * rsqrtf(var + EPSF);
        float val = fmaxf(fmaf(a.h2[(size_t)r * HP + k], s, a.vbe2[k] - mu * s), 0.f);
        p = fmaf(val, a.vW3[k], p);
      }
      sred[tid] = p; __syncthreads();
      for (int st = 128; st > 0; st >>= 1) {
        if (tid < st) sred[tid] += sred[tid + st];
        __syncthreads();
      }
      if (tid == 0) {
        float y = sred[0] + a.vb3[0];
        a.yraw[r] = y;
        atomicAdd(s2, y); atomicAdd(q2, y * y);
      }
      __syncthreads();
    }
  }
  gsync(cnt, gen, nb);
  // ---- v0 stage 4 ----
  {
    const float* s2 = stats + 102*2*HP; const float* q2 = s2 + HP;
    float mu = s2[0] * invB, var = q2[0] * invB - mu * mu;
    float rs = rsqrtf(var + EPSF);
    for (int idx = bid * 256 + tid; idx < B_; idx += nb * 256)
      a.v[idx] = fmaxf(a.vg3[0] * (a.yraw[idx] - mu) * rs + a.vbe3[0], 0.f);
  }
  gsync(cnt, gen, nb);

  // ---- scan ----
  for (int i = 0; i < S_; ++i) {
    const float* xc = a.path + (size_t)i * B_ * D_;
    float* xn       = a.path + (size_t)(i + 1) * B_ * D_;
    float t0 = a.tg[i], t1 = a.tg[i + 1];
    float hi = t1 - t0, sq = sqrtf(hi);
    float* s0 = stats + (size_t)(2*i)   * 2 * HP; float* q0 = s0 + HP;
    float* s1 = stats + (size_t)(2*i+1) * 2 * HP; float* q1 = s1 + HP;

    // stage A: gemm1 (stats) + alpha-hidden
    for (int t = bid; t < 192; t += nb) {
      int tt = (t < 96) ? t : t - 96;
      int c0 = (tt % 3) * 128, r0 = (tt / 3) * 128;
      f32x4 acc[4][4];
      if (t < 96) {
        gemm_tile(xc, D_, D_, 0, nullptr, nullptr, nullptr, nullptr, invB,
                  a.W1t + (size_t)i * H_ * 256, 256, H_, r0, c0, As, Ws, sc, sh, acc);
        epi_store(a.h1, HP, H_, r0, c0, a.b1 + (size_t)i * H_, nullptr, 0.f, 0, s0, q0, acc);
      } else {
        gemm_tile(xc, D_, D_, 0, nullptr, nullptr, nullptr, nullptr, invB,
                  a.aW1t, 256, H_, r0, c0, As, Ws, sc, sh, acc);
        epi_store(a.ah, HP, H_, r0, c0, a.ab1, a.aW1, t0, 1, nullptr, nullptr, acc);
      }
    }
    gsync(cnt, gen, nb);

    // stage B: gemm2 (BN on h1, stats)
    for (int t = bid; t < 96; t += nb) {
      int c0 = (t % 3) * 128, r0 = (t / 3) * 128;
      f32x4 acc[4][4];
      gemm_tile(a.h1, HP, H_, 1, a.g1 + (size_t)i * H_, a.be1 + (size_t)i * H_, s0, q0, invB,
                a.W2t + (size_t)i * H_ * 288, 288, H_, r0, c0, As, Ws, sc, sh, acc);
      epi_store(a.h2, HP, H_, r0, c0, a.b2 + (size_t)i * H_, nullptr, 0.f, 0, s1, q1, acc);
    }
    gsync(cnt, gen, nb);

    // stage C: grad (fused ito) + alpha (fused update)
    for (int t = bid; t < 128; t += nb) {
      int tt = t & 63;
      int c0 = (tt & 1) * 128, r0 = (tt >> 1) * 128;
      f32x4 acc[4][4];
      if (t < 64) {
        gemm_tile(a.h2, HP, H_, 1, a.g2 + (size_t)i * H_, a.be2 + (size_t)i * H_, s1, q1, invB,
                  a.W3t + (size_t)i * D_ * 288, 288, D_, r0, c0, As, Ws, sc, sh, acc);
        epi_grad(a.b3 + (size_t)i * D_, a.xi + (size_t)i * B_ * D_, a.v, sq, r0, c0, acc);
      } else {
        gemm_tile(a.ah, HP, H_, 0, nullptr, nullptr, nullptr, nullptr, invB,
                  a.aW2t, 288, D_, r0, c0, As, Ws, sc, sh, acc);
        epi_alpha(a.ab2, xc, a.xi + (size_t)i * B_ * D_, a.law + (size_t)i * D_,
                  xn, a.v, hi, sq, r0, c0, acc);
      }
    }
    gsync(cnt, gen, nb);
  }
}

// ---------------- weight transpose+cast (7 jobs, one launch) ----------------
struct WJob { const float* in; bf16_t* out; int K, N, Kp, total; };
struct WJobs { WJob j[7]; };

__global__ __launch_bounds__(256) void wconv7(WJobs js) {
  WJob jb = js.j[blockIdx.y];
  for (int idx = blockIdx.x * 256 + threadIdx.x; idx < jb.total; idx += gridDim.x * 256) {
    int k = idx % jb.Kp; int rest = idx / jb.Kp; int n = rest % jb.N; int s = rest / jb.N;
    float v = (k < jb.K) ? jb.in[((size_t)s * jb.K + k) * jb.N + n] : 0.f;
    jb.out[idx] = (bf16_t)v;
  }
}

// ---------------- host ------------------------------------------------------
extern "C" void kernel_launch(void* const* d_in, const int* in_sizes, int n_in,
                              void* d_out, int out_size, void* d_ws, size_t ws_size,
                              hipStream_t stream) {
  const float* x    = (const float*)d_in[0];
  const float* W1   = (const float*)d_in[1];
  const float* b1   = (const float*)d_in[2];
  const float* g1   = (const float*)d_in[3];
  const float* be1  = (const float*)d_in[4];
  const float* W2   = (const float*)d_in[5];
  const float* b2   = (const float*)d_in[6];
  const float* g2   = (const float*)d_in[7];
  const float* be2  = (const float*)d_in[8];
  const float* W3   = (const float*)d_in[9];
  const float* b3   = (const float*)d_in[10];
  const float* vW1  = (const float*)d_in[11];
  const float* vb1  = (const float*)d_in[12];
  const float* vg1  = (const float*)d_in[13];
  const float* vbe1 = (const float*)d_in[14];
  const float* vW2  = (const float*)d_in[15];
  const float* vb2  = (const float*)d_in[16];
  const float* vg2  = (const float*)d_in[17];
  const float* vbe2 = (const float*)d_in[18];
  const float* vW3  = (const float*)d_in[19];
  const float* vb3  = (const float*)d_in[20];
  const float* vg3  = (const float*)d_in[21];
  const float* vbe3 = (const float*)d_in[22];
  const float* aW1  = (const float*)d_in[23];
  const float* ab1  = (const float*)d_in[24];
  const float* aW2  = (const float*)d_in[25];
  const float* ab2  = (const float*)d_in[26];
  const float* law  = (const float*)d_in[27];
  const float* tg   = (const float*)d_in[28];
  const float* xi   = (const float*)d_in[29];

  float* out    = (float*)d_out;
  float* v_out  = out;
  float* xf_out = out + B_;
  float* path   = out + B_ + (size_t)B_ * D_;

  float* ws    = (float*)d_ws;
  float* h1    = ws;
  float* h2    = h1 + (size_t)B_ * HP;
  float* ah    = h2 + (size_t)B_ * HP;
  float* yraw  = ah + (size_t)B_ * HP;
  float* stats = yraw + B_;                      // 103 * 2 * HP floats
  const int NSLOT = 103;
  unsigned* bar = (unsigned*)(stats + (size_t)NSLOT * 2 * HP);   // 16 floats reserved
  bf16_t* wbuf = (bf16_t*)((float*)bar + 16);

  bf16_t* W1t  = wbuf;                                  // [50][266][256]
  bf16_t* W2t  = W1t  + (size_t)S_ * H_ * 256;          // [50][266][288]
  bf16_t* W3t  = W2t  + (size_t)S_ * H_ * 288;          // [50][256][288]
  bf16_t* aW1t = W3t  + (size_t)S_ * D_ * 288;          // [266][256]
  bf16_t* aW2t = aW1t + (size_t)H_ * 256;               // [256][288]
  bf16_t* vW1t = aW2t + (size_t)D_ * 288;               // [266][256]
  bf16_t* vW2t = vW1t + (size_t)H_ * 256;               // [266][288]

  hipMemsetAsync(stats, 0, (size_t)NSLOT * 2 * HP * sizeof(float) + 64, stream);
  hipMemcpyAsync(path, x, (size_t)B_ * D_ * sizeof(float), hipMemcpyDeviceToDevice, stream);

  WJobs js;
  js.j[0] = {W1,        W1t,  D_, H_, 256, S_ * H_ * 256};
  js.j[1] = {W2,        W2t,  H_, H_, 288, S_ * H_ * 288};
  js.j[2] = {W3,        W3t,  H_, D_, 288, S_ * D_ * 288};
  js.j[3] = {aW1 + H_,  aW1t, D_, H_, 256, H_ * 256};
  js.j[4] = {aW2,       aW2t, H_, D_, 288, D_ * 288};
  js.j[5] = {vW1,       vW1t, D_, H_, 256, H_ * 256};
  js.j[6] = {vW2,       vW2t, H_, H_, 288, H_ * 288};
  wconv7<<<dim3(256, 7), dim3(256), 0, stream>>>(js);

  ScanArgs a;
  a.path = path; a.v = v_out;
  a.h1 = h1; a.h2 = h2; a.ah = ah; a.yraw = yraw;
  a.stats = stats;
  a.W1t = W1t; a.W2t = W2t; a.W3t = W3t; a.aW1t = aW1t; a.aW2t = aW2t;
  a.vW1t = vW1t; a.vW2t = vW2t;
  a.b1 = b1; a.g1 = g1; a.be1 = be1; a.b2 = b2; a.g2 = g2; a.be2 = be2; a.b3 = b3;
  a.vb1 = vb1; a.vg1 = vg1; a.vbe1 = vbe1; a.vb2 = vb2; a.vg2 = vg2; a.vbe2 = vbe2;
  a.vW3 = vW3; a.vb3 = vb3; a.vg3 = vg3; a.vbe3 = vbe3;
  a.ab1 = ab1; a.ab2 = ab2; a.aW1 = aW1; a.law = law; a.tg = tg; a.xi = xi;
  a.bar = bar;

  scan_kernel<<<dim3(NB), dim3(256), 0, stream>>>(a);

  hipMemcpyAsync(xf_out, path + (size_t)S_ * B_ * D_,
                 (size_t)B_ * D_ * sizeof(float), hipMemcpyDeviceToDevice, stream);
}